// Round 7
// baseline (247.949 us; speedup 1.0000x reference)
//
#include <hip/hip_runtime.h>
#include <hip/hip_bf16.h>
#include <hip/hip_fp16.h>

#define NN 100000
#define NE 1600000
constexpr int NN_PAD = 100032;              // 64-row padded (1563 blocks)
constexpr int NBUK = (NN + 255) / 256;      // 391 dst buckets of 256 nodes
constexpr int CH   = 4096;                  // edges per chunk
constexpr int EPT  = CH / 256;              // 16 edges per thread
constexpr int NCHK = (NE + CH - 1) / CH;    // 391 chunks
constexpr int LCNT = NBUK * NCHK;           // 152,881 counters
constexpr int SCB  = (LCNT + 1023) / 1024;  // 150 scan blocks

typedef _Float16 f16x8 __attribute__((ext_vector_type(8)));
typedef float f32x4 __attribute__((ext_vector_type(4)));
typedef unsigned short u16x8 __attribute__((ext_vector_type(8)));

__device__ __forceinline__ float h2f(unsigned short h) {
    return __half2float(__ushort_as_half(h));
}
__device__ __forceinline__ unsigned short f2h(float f) {
    return __half_as_ushort(__float2half(f));  // RN
}

// ---------------- edge dtype detection ----------------
__global__ void k_detect_i64(const unsigned* __restrict__ ei, int* __restrict__ flag) {
    __shared__ int any_nz;
    if (threadIdx.x == 0) any_nz = 0;
    __syncthreads();
    int nz = 0;
    for (int i = threadIdx.x; i < 2048; i += 256)
        if (ei[2 * i + 1] != 0u) nz = 1;
    if (nz) atomicExch(&any_nz, 1);
    __syncthreads();
    if (threadIdx.x == 0) *flag = (any_nz == 0) ? 1 : 0;
}

__device__ __forceinline__ int edge_at(const void* ei, int is64, long long idx) {
    if (is64) return (int)((const long long*)ei)[idx];
    return ((const int*)ei)[idx];
}

// ---------------- CSR build: pass 1, per-chunk LDS bucket histogram ----------------
__global__ __launch_bounds__(256) void k_count(const void* __restrict__ ei,
                                               const int* __restrict__ flag,
                                               int* __restrict__ counts) {
    __shared__ int cnt[NBUK];
    const int t = threadIdx.x, blk = blockIdx.x;
    for (int i = t; i < NBUK; i += 256) cnt[i] = 0;
    __syncthreads();
    const int is64 = *flag;
    const int e0 = blk * CH;
    const int elim = min(NE, e0 + CH);
#pragma unroll
    for (int j = 0; j < EPT; j++) {
        int e = e0 + j * 256 + t;
        if (e < elim) {
            int s = edge_at(ei, is64, e);
            int d = edge_at(ei, is64, (long long)NE + e);
            if ((unsigned)s < NN && (unsigned)d < NN) atomicAdd(&cnt[d >> 8], 1);
        }
    }
    __syncthreads();
    for (int i = t; i < NBUK; i += 256) counts[(size_t)i * NCHK + blk] = cnt[i];
}

// ---------------- exclusive scan of counts[LCNT] (in place) ----------------
__global__ void k_scan1v(int* __restrict__ data, int* __restrict__ bsum) {
    __shared__ int lds[256];
    int t = threadIdx.x, b = blockIdx.x;
    int base = b * 1024 + t * 4;
    int v0 = (base + 0 < LCNT) ? data[base + 0] : 0;
    int v1 = (base + 1 < LCNT) ? data[base + 1] : 0;
    int v2 = (base + 2 < LCNT) ? data[base + 2] : 0;
    int v3 = (base + 3 < LCNT) ? data[base + 3] : 0;
    lds[t] = v0 + v1 + v2 + v3;
    __syncthreads();
    for (int off = 1; off < 256; off <<= 1) {
        int x = (t >= off) ? lds[t - off] : 0;
        __syncthreads();
        lds[t] += x;
        __syncthreads();
    }
    int excl = (t > 0) ? lds[t - 1] : 0;
    if (t == 255) bsum[b] = lds[255];
    if (base + 0 < LCNT) data[base + 0] = excl;
    if (base + 1 < LCNT) data[base + 1] = excl + v0;
    if (base + 2 < LCNT) data[base + 2] = excl + v0 + v1;
    if (base + 3 < LCNT) data[base + 3] = excl + v0 + v1 + v2;
}

__global__ void k_scan2v(int* __restrict__ bsum) {
    __shared__ int lds[256];
    int t = threadIdx.x;
    int v = (t < SCB) ? bsum[t] : 0;
    lds[t] = v;
    __syncthreads();
    for (int off = 1; off < 256; off <<= 1) {
        int x = (t >= off) ? lds[t - off] : 0;
        __syncthreads();
        lds[t] += x;
        __syncthreads();
    }
    if (t < SCB) bsum[t] = lds[t] - v;  // exclusive
    if (t == SCB - 1) bsum[SCB] = lds[t];  // total valid edges
}

__global__ void k_scan3v(int* __restrict__ data, const int* __restrict__ bsum) {
    int i = blockIdx.x * 256 + threadIdx.x;
    if (i < LCNT) data[i] += bsum[i >> 10];
    else if (i == LCNT) data[LCNT] = bsum[SCB];
}

// ---------------- CSR build: pass 2, chunk -> LDS bucket-sort -> reserved slots ----------------
__global__ __launch_bounds__(256) void k_scatter2(const void* __restrict__ ei,
                                                  const int* __restrict__ flag,
                                                  const int* __restrict__ scanned,
                                                  unsigned* __restrict__ staging) {
    __shared__ int cnt[512], excl[512], cur[512], gbase[512];
    __shared__ unsigned lbuf[CH];
    __shared__ unsigned short lbkt[CH];
    const int t = threadIdx.x, blk = blockIdx.x;
    cnt[t] = 0; cnt[t + 256] = 0;
    __syncthreads();
    const int is64 = *flag;
    const int e0 = blk * CH;
    const int elim = min(NE, e0 + CH);
    unsigned recs[EPT];
    int bkts[EPT];
#pragma unroll
    for (int j = 0; j < EPT; j++) {
        int e = e0 + j * 256 + t;
        int bk = -1; unsigned rc = 0;
        if (e < elim) {
            int s = edge_at(ei, is64, e);
            int d = edge_at(ei, is64, (long long)NE + e);
            if ((unsigned)s < NN && (unsigned)d < NN) {
                bk = d >> 8;
                rc = (unsigned)s | ((unsigned)(d & 255) << 17);
                atomicAdd(&cnt[bk], 1);
            }
        }
        recs[j] = rc; bkts[j] = bk;
    }
    __syncthreads();
    excl[t] = cnt[t]; excl[t + 256] = cnt[t + 256];
    __syncthreads();
    for (int off = 1; off < 512; off <<= 1) {
        int a0 = (t >= off) ? excl[t - off] : 0;
        int a1 = (t + 256 >= off) ? excl[t + 256 - off] : 0;
        __syncthreads();
        excl[t] += a0; excl[t + 256] += a1;
        __syncthreads();
    }
    int i0 = excl[t] - cnt[t], i1 = excl[t + 256] - cnt[t + 256];
    excl[t] = i0; excl[t + 256] = i1;
    cur[t] = i0; cur[t + 256] = i1;
    for (int b = t; b < NBUK; b += 256) gbase[b] = scanned[(size_t)b * NCHK + blk];
    __syncthreads();
#pragma unroll
    for (int j = 0; j < EPT; j++) {
        if (bkts[j] >= 0) {
            int pos = atomicAdd(&cur[bkts[j]], 1);
            lbuf[pos] = recs[j];
            lbkt[pos] = (unsigned short)bkts[j];
        }
    }
    __syncthreads();
    const int tot = excl[NBUK];
    for (int i = t; i < tot; i += 256) {
        int b = lbkt[i];
        staging[(size_t)gbase[b] + (i - excl[b])] = lbuf[i];
    }
}

// ---------------- CSR build: pass 3, per-bucket deg/row_off/dinv + sorted csr ----------------
__global__ __launch_bounds__(256) void k_phaseB2(const unsigned* __restrict__ staging,
                                                 const int* __restrict__ scanned,
                                                 float* __restrict__ dinv,
                                                 int* __restrict__ row_off,
                                                 int* __restrict__ csr) {
    __shared__ int cnt[256], excl[256], cur[256];
    __shared__ int buf[8192];
    const int t = threadIdx.x, b = blockIdx.x;
    const int node0 = b << 8;
    const int nlocal = min(256, NN - node0);
    const int seg_beg = scanned[(size_t)b * NCHK];
    const size_t nxt = (size_t)(b + 1) * NCHK;
    const int seg_end = scanned[nxt > (size_t)LCNT ? (size_t)LCNT : nxt];
    const int len = min(seg_end - seg_beg, 8192);
    cnt[t] = 0;
    __syncthreads();
    for (int i = t; i < len; i += 256) {
        unsigned r = staging[seg_beg + i];
        atomicAdd(&cnt[r >> 17], 1);
    }
    __syncthreads();
    excl[t] = cnt[t];
    __syncthreads();
    for (int off = 1; off < 256; off <<= 1) {
        int x = (t >= off) ? excl[t - off] : 0;
        __syncthreads();
        excl[t] += x;
        __syncthreads();
    }
    int ex = excl[t] - cnt[t];
    excl[t] = ex;
    cur[t] = ex;
    if (t < nlocal) {
        row_off[node0 + t] = seg_beg + ex;
        dinv[node0 + t] = rsqrtf((float)(cnt[t] + 1));  // +1 self loop
    }
    if (b == NBUK - 1 && t == 0) row_off[NN] = seg_end;
    __syncthreads();
    for (int i = t; i < len; i += 256) {
        unsigned r = staging[seg_beg + i];
        int pos = atomicAdd(&cur[r >> 17], 1);
        buf[pos] = (int)(r & 0x1FFFFu);
    }
    __syncthreads();
    for (int i = t; i < len; i += 256) csr[seg_beg + i] = buf[i];
}

// ---------------- W pack: f32 W[k][n] -> f16 frag array ----------------
template <int C>
__global__ void k_packW(const float* __restrict__ W, _Float16* __restrict__ P) {
    constexpr int NT = C / 16;
    int i = blockIdx.x * 256 + threadIdx.x;
    if (i >= 4 * NT * 512) return;
    int j = i & 7, lane = (i >> 3) & 63;
    int rest = i >> 9;
    int ct = rest % NT, kc = rest / NT;
    int k = kc * 32 + (lane >> 4) * 8 + j;
    int n = ct * 16 + (lane & 15);
    P[i] = (_Float16)W[k * C + n];
}

// ---------------- MFMA GEMM: Hf16[n,:] = f16(dinv[n] * (X[n,:] @ W)) ----------------
template <int C, bool F32SRC>
__global__ __launch_bounds__(256) void k_mgemm(const void* __restrict__ Xv,
                                               const _Float16* __restrict__ P,
                                               const float* __restrict__ dinv,
                                               unsigned short* __restrict__ H) {
    constexpr int NT = C / 16;
    const int tid = threadIdx.x, w = tid >> 6, lane = tid & 63;
    const int lr = lane & 15, lg = lane >> 4;
    const int row = blockIdx.x * 64 + w * 16 + lr;
    const int arow = F32SRC ? min(row, NN - 1) : row;
    f32x4 acc[NT];
#pragma unroll
    for (int t = 0; t < NT; t++) acc[t] = (f32x4){0.f, 0.f, 0.f, 0.f};
    const f16x8* __restrict__ Pp = (const f16x8*)P;
#pragma unroll
    for (int kc = 0; kc < 4; kc++) {
        f16x8 a;
        if (F32SRC) {
            const float* xp = (const float*)Xv + (size_t)arow * 128 + kc * 32 + lg * 8;
            float4 x0 = *(const float4*)xp;
            float4 x1 = *(const float4*)(xp + 4);
            a[0] = (_Float16)x0.x; a[1] = (_Float16)x0.y;
            a[2] = (_Float16)x0.z; a[3] = (_Float16)x0.w;
            a[4] = (_Float16)x1.x; a[5] = (_Float16)x1.y;
            a[6] = (_Float16)x1.z; a[7] = (_Float16)x1.w;
        } else {
            a = *(const f16x8*)((const _Float16*)Xv + (size_t)arow * 128 + kc * 32 + lg * 8);
        }
#pragma unroll
        for (int t = 0; t < NT; t++) {
            f16x8 b = Pp[(kc * NT + t) * 64 + lane];
            acc[t] = __builtin_amdgcn_mfma_f32_16x16x32_f16(a, b, acc[t], 0, 0, 0);
        }
    }
    const int orow0 = blockIdx.x * 64 + w * 16 + lg * 4;
    float dv[4];
#pragma unroll
    for (int r = 0; r < 4; r++) dv[r] = dinv[orow0 + r];
#pragma unroll
    for (int t = 0; t < NT; t++)
#pragma unroll
        for (int r = 0; r < 4; r++)
            H[(size_t)(orow0 + r) * C + t * 16 + lr] = f2h(acc[t][r] * dv[r]);
}

// ---------------- Aggregation C=128 (f16 H): 4 nodes/wave, 16B loads, f16 out ------
template <bool RELU>
__global__ __launch_bounds__(256) void k_agg128(const unsigned short* __restrict__ H,
                                                const int* __restrict__ row_off,
                                                const int* __restrict__ csr,
                                                const float* __restrict__ dinv,
                                                const float* __restrict__ bias,
                                                unsigned short* __restrict__ OUT) {
    const int tid = threadIdx.x;
    const int wid = tid >> 6, lane = tid & 63;
    const int q = lane >> 4, il = lane & 15;
    const int node = blockIdx.x * 16 + wid * 4 + q;  // NN = 6250*16 exactly
    const int beg = row_off[node];
    const int cnt = row_off[node + 1] - beg;
    int m1 = max(cnt, __shfl(cnt, lane ^ 16));
    const int tmax = max(m1, __shfl(m1, lane ^ 32));
    const u16x8* __restrict__ Hh = (const u16x8*)H;  // 16 u16x8 per row
    float acc[8] = {0.f, 0.f, 0.f, 0.f, 0.f, 0.f, 0.f, 0.f};
    for (int j0 = 0; j0 < tmax; j0 += 16) {
        int sidx = node;
        if (j0 + il < cnt) sidx = csr[beg + j0 + il];
        const int rem = min(16, tmax - j0);
        for (int u = 0; u < rem; u += 8) {
            u16x8 v[8]; float m[8];
#pragma unroll
            for (int k = 0; k < 8; k++) {
                int s = __shfl(sidx, q * 16 + u + k);
                v[k] = Hh[(size_t)s * 16 + il];
                m[k] = (j0 + u + k < cnt) ? 1.f : 0.f;
            }
#pragma unroll
            for (int k = 0; k < 8; k++)
#pragma unroll
                for (int e = 0; e < 8; e++)
                    acc[e] = fmaf(m[k], h2f(v[k][e]), acc[e]);
        }
    }
    u16x8 hv = Hh[(size_t)node * 16 + il];
#pragma unroll
    for (int e = 0; e < 8; e++) acc[e] += h2f(hv[e]);
    const float dv = dinv[node];
    float4 b0 = *(const float4*)&bias[il * 8];
    float4 b1 = *(const float4*)&bias[il * 8 + 4];
    float ob[8] = {b0.x, b0.y, b0.z, b0.w, b1.x, b1.y, b1.z, b1.w};
    u16x8 oh;
#pragma unroll
    for (int e = 0; e < 8; e++) {
        float o = fmaf(acc[e], dv, ob[e]);
        if (RELU) o = fmaxf(o, 0.f);
        oh[e] = f2h(o);
    }
    ((u16x8*)OUT)[(size_t)node * 16 + il] = oh;
}

// ---------------- Aggregation C=64 (f16 H): 8 nodes/wave, 16B loads, f32 out -------
__global__ __launch_bounds__(256) void k_agg64(const unsigned short* __restrict__ H,
                                               const int* __restrict__ row_off,
                                               const int* __restrict__ csr,
                                               const float* __restrict__ dinv,
                                               const float* __restrict__ bias,
                                               float* __restrict__ OUT) {
    const int tid = threadIdx.x;
    const int wid = tid >> 6, lane = tid & 63;
    const int q = lane >> 3, il = lane & 7;
    const int node = blockIdx.x * 32 + wid * 8 + q;  // NN = 3125*32 exactly
    const int beg = row_off[node];
    const int cnt = row_off[node + 1] - beg;
    int m1 = max(cnt, __shfl(cnt, lane ^ 8));
    m1 = max(m1, __shfl(m1, lane ^ 16));
    const int tmax = max(m1, __shfl(m1, lane ^ 32));
    const u16x8* __restrict__ Hh = (const u16x8*)H;  // 8 u16x8 per row
    float acc[8] = {0.f, 0.f, 0.f, 0.f, 0.f, 0.f, 0.f, 0.f};
    for (int j0 = 0; j0 < tmax; j0 += 8) {
        int sidx = node;
        if (j0 + il < cnt) sidx = csr[beg + j0 + il];
        u16x8 v[8]; float m[8];
#pragma unroll
        for (int k = 0; k < 8; k++) {
            int s = __shfl(sidx, q * 8 + k);
            v[k] = Hh[(size_t)s * 8 + il];
            m[k] = (j0 + k < cnt) ? 1.f : 0.f;
        }
#pragma unroll
        for (int k = 0; k < 8; k++)
#pragma unroll
            for (int e = 0; e < 8; e++)
                acc[e] = fmaf(m[k], h2f(v[k][e]), acc[e]);
    }
    u16x8 hv = Hh[(size_t)node * 8 + il];
#pragma unroll
    for (int e = 0; e < 8; e++) acc[e] += h2f(hv[e]);
    const float dv = dinv[node];
    float4 b0 = *(const float4*)&bias[il * 8];
    float4 b1 = *(const float4*)&bias[il * 8 + 4];
    float ob[8] = {b0.x, b0.y, b0.z, b0.w, b1.x, b1.y, b1.z, b1.w};
    float4 o0, o1;
    o0.x = fmaf(acc[0], dv, ob[0]); o0.y = fmaf(acc[1], dv, ob[1]);
    o0.z = fmaf(acc[2], dv, ob[2]); o0.w = fmaf(acc[3], dv, ob[3]);
    o1.x = fmaf(acc[4], dv, ob[4]); o1.y = fmaf(acc[5], dv, ob[5]);
    o1.z = fmaf(acc[6], dv, ob[6]); o1.w = fmaf(acc[7], dv, ob[7]);
    *(float4*)&OUT[(size_t)node * 64 + il * 8] = o0;
    *(float4*)&OUT[(size_t)node * 64 + il * 8 + 4] = o1;
}

extern "C" void kernel_launch(void* const* d_in, const int* in_sizes, int n_in,
                              void* d_out, int out_size, void* d_ws, size_t ws_size,
                              hipStream_t stream) {
    const float* x  = (const float*)d_in[0];
    const void*  ei = d_in[1];
    const float* W1 = (const float*)d_in[2];
    const float* b1 = (const float*)d_in[3];
    const float* W2 = (const float*)d_in[4];
    const float* b2 = (const float*)d_in[5];
    const float* W3 = (const float*)d_in[6];
    const float* b3 = (const float*)d_in[7];
    float* out = (float*)d_out;

    char* wsp = (char*)d_ws;
    size_t off = 0;
    auto alloc = [&](size_t bytes) -> void* {
        void* p = wsp + off;
        off += (bytes + 255) & ~(size_t)255;
        return p;
    };
    unsigned short* G = (unsigned short*)alloc((size_t)NN_PAD * 128 * 2);  // GEMM out (f16)
    unsigned short* F = (unsigned short*)alloc((size_t)NN_PAD * 128 * 2);  // agg out (f16)
    float* dinv    = (float*)alloc((size_t)NN_PAD * 4);
    int*   row_off = (int*)alloc(((size_t)NN + 1) * 4);
    int*   counts  = (int*)alloc(((size_t)LCNT + 1) * 4);
    int*   bsum    = (int*)alloc(((size_t)SCB + 1) * 4);
    int*   csr     = (int*)alloc((size_t)NE * 4);
    _Float16* P1   = (_Float16*)alloc((size_t)128 * 128 * 2);
    _Float16* P2   = (_Float16*)alloc((size_t)128 * 128 * 2);
    _Float16* P3   = (_Float16*)alloc((size_t)128 * 64 * 2);
    int*   flag    = (int*)alloc(256);
    if (off > ws_size) return;

    unsigned* staging = (unsigned*)G;  // aliases G (dead until gemm layer 1)

    k_detect_i64<<<1, 256, 0, stream>>>((const unsigned*)ei, flag);
    k_count<<<NCHK, 256, 0, stream>>>(ei, flag, counts);
    k_scan1v<<<SCB, 256, 0, stream>>>(counts, bsum);
    k_scan2v<<<1, 256, 0, stream>>>(bsum);
    k_scan3v<<<(LCNT + 1 + 255) / 256, 256, 0, stream>>>(counts, bsum);
    k_scatter2<<<NCHK, 256, 0, stream>>>(ei, flag, counts, staging);
    k_phaseB2<<<NBUK, 256, 0, stream>>>(staging, counts, dinv, row_off, csr);

    k_packW<128><<<64, 256, 0, stream>>>(W1, P1);
    k_packW<128><<<64, 256, 0, stream>>>(W2, P2);
    k_packW<64><<<32, 256, 0, stream>>>(W3, P3);

    constexpr int NBLK = NN_PAD / 64;  // 1563
    k_mgemm<128, true><<<NBLK, 256, 0, stream>>>(x, P1, dinv, G);
    k_agg128<true><<<NN / 16, 256, 0, stream>>>(G, row_off, csr, dinv, b1, F);
    k_mgemm<128, false><<<NBLK, 256, 0, stream>>>(F, P2, dinv, G);
    k_agg128<true><<<NN / 16, 256, 0, stream>>>(G, row_off, csr, dinv, b2, F);
    k_mgemm<64, false><<<NBLK, 256, 0, stream>>>(F, P3, dinv, G);
    k_agg64<<<NN / 32, 256, 0, stream>>>(G, row_off, csr, dinv, b3, out);
}

// Round 8
// 245.431 us; speedup vs baseline: 1.0103x; 1.0103x over previous
//
#include <hip/hip_runtime.h>
#include <hip/hip_bf16.h>
#include <hip/hip_fp16.h>

#define NN 100000
#define NE 1600000
constexpr int NN_PAD = 100032;              // 64-row padded (1563 blocks)
constexpr int NBUK = (NN + 255) / 256;      // 391 dst buckets of 256 nodes
constexpr int CH   = 2048;                  // edges per chunk
constexpr int EPT  = CH / 256;              // 8 edges per thread
constexpr int NCHK = (NE + CH - 1) / CH;    // 782 chunks
constexpr int LCNT = NBUK * NCHK;           // 305,762 counters
constexpr int SCB  = (LCNT + 2047) / 2048;  // 150 scan blocks (2048/block)

typedef _Float16 f16x8 __attribute__((ext_vector_type(8)));
typedef float f32x4 __attribute__((ext_vector_type(4)));
typedef unsigned short u16x8 __attribute__((ext_vector_type(8)));

__device__ __forceinline__ float h2f(unsigned short h) {
    return __half2float(__ushort_as_half(h));
}
__device__ __forceinline__ unsigned short f2h(float f) {
    return __half_as_ushort(__float2half(f));  // RN
}

// ---------------- edge dtype detection + dinv tail init ----------------
__global__ void k_detect_i64(const unsigned* __restrict__ ei, int* __restrict__ flag,
                             float* __restrict__ dinv) {
    __shared__ int any_nz;
    if (threadIdx.x == 0) any_nz = 0;
    __syncthreads();
    int nz = 0;
    for (int i = threadIdx.x; i < 2048; i += 256)
        if (ei[2 * i + 1] != 0u) nz = 1;
    if (nz) atomicExch(&any_nz, 1);
    if (threadIdx.x < NN_PAD - NN) dinv[NN + threadIdx.x] = 0.f;  // pad rows -> 0
    __syncthreads();
    if (threadIdx.x == 0) *flag = (any_nz == 0) ? 1 : 0;
}

__device__ __forceinline__ int edge_at(const void* ei, int is64, long long idx) {
    if (is64) return (int)((const long long*)ei)[idx];
    return ((const int*)ei)[idx];
}

// ---------------- CSR build: pass 1, per-chunk LDS bucket histogram ----------------
__global__ __launch_bounds__(256) void k_count(const void* __restrict__ ei,
                                               const int* __restrict__ flag,
                                               int* __restrict__ counts) {
    __shared__ int cnt[NBUK];
    const int t = threadIdx.x, blk = blockIdx.x;
    for (int i = t; i < NBUK; i += 256) cnt[i] = 0;
    __syncthreads();
    const int is64 = *flag;
    const int e0 = blk * CH;
    const int elim = min(NE, e0 + CH);
#pragma unroll
    for (int j = 0; j < EPT; j++) {
        int e = e0 + j * 256 + t;
        if (e < elim) {
            int s = edge_at(ei, is64, e);
            int d = edge_at(ei, is64, (long long)NE + e);
            if ((unsigned)s < NN && (unsigned)d < NN) atomicAdd(&cnt[d >> 8], 1);
        }
    }
    __syncthreads();
    for (int i = t; i < NBUK; i += 256) counts[(size_t)i * NCHK + blk] = cnt[i];
}

// ---------------- exclusive scan of counts[LCNT] (in place), 2048/block ------------
__global__ void k_scan1v(int* __restrict__ data, int* __restrict__ bsum) {
    __shared__ int lds[256];
    int t = threadIdx.x, b = blockIdx.x;
    int base = b * 2048 + t * 8;
    int v[8], s = 0;
#pragma unroll
    for (int j = 0; j < 8; j++) {
        v[j] = (base + j < LCNT) ? data[base + j] : 0;
        s += v[j];
    }
    lds[t] = s;
    __syncthreads();
    for (int off = 1; off < 256; off <<= 1) {
        int x = (t >= off) ? lds[t - off] : 0;
        __syncthreads();
        lds[t] += x;
        __syncthreads();
    }
    int run = (t > 0) ? lds[t - 1] : 0;
    if (t == 255) bsum[b] = lds[255];
#pragma unroll
    for (int j = 0; j < 8; j++) {
        if (base + j < LCNT) data[base + j] = run;
        run += v[j];
    }
}

__global__ void k_scan2v(int* __restrict__ bsum) {
    __shared__ int lds[256];
    int t = threadIdx.x;
    int v = (t < SCB) ? bsum[t] : 0;
    lds[t] = v;
    __syncthreads();
    for (int off = 1; off < 256; off <<= 1) {
        int x = (t >= off) ? lds[t - off] : 0;
        __syncthreads();
        lds[t] += x;
        __syncthreads();
    }
    if (t < SCB) bsum[t] = lds[t] - v;  // exclusive
    if (t == SCB - 1) bsum[SCB] = lds[t];  // total valid edges
}

__global__ void k_scan3v(int* __restrict__ data, const int* __restrict__ bsum) {
    int i = blockIdx.x * 256 + threadIdx.x;
    if (i < LCNT) data[i] += bsum[i >> 11];      // 2048 elems per scan1 block
    else if (i == LCNT) data[LCNT] = bsum[SCB];
}

// ---------------- CSR build: pass 2, chunk -> LDS bucket-sort -> reserved slots ----
__global__ __launch_bounds__(256) void k_scatter2(const void* __restrict__ ei,
                                                  const int* __restrict__ flag,
                                                  const int* __restrict__ scanned,
                                                  unsigned* __restrict__ staging) {
    __shared__ int cnt[512], excl[512], cur[512], gbase[512];
    __shared__ unsigned lbuf[CH];
    __shared__ unsigned short lbkt[CH];
    const int t = threadIdx.x, blk = blockIdx.x;
    cnt[t] = 0; cnt[t + 256] = 0;
    __syncthreads();
    const int is64 = *flag;
    const int e0 = blk * CH;
    const int elim = min(NE, e0 + CH);
    unsigned recs[EPT];
    int bkts[EPT];
#pragma unroll
    for (int j = 0; j < EPT; j++) {
        int e = e0 + j * 256 + t;
        int bk = -1; unsigned rc = 0;
        if (e < elim) {
            int s = edge_at(ei, is64, e);
            int d = edge_at(ei, is64, (long long)NE + e);
            if ((unsigned)s < NN && (unsigned)d < NN) {
                bk = d >> 8;
                rc = (unsigned)s | ((unsigned)(d & 255) << 17);
                atomicAdd(&cnt[bk], 1);
            }
        }
        recs[j] = rc; bkts[j] = bk;
    }
    __syncthreads();
    excl[t] = cnt[t]; excl[t + 256] = cnt[t + 256];
    __syncthreads();
    for (int off = 1; off < 512; off <<= 1) {
        int a0 = (t >= off) ? excl[t - off] : 0;
        int a1 = (t + 256 >= off) ? excl[t + 256 - off] : 0;
        __syncthreads();
        excl[t] += a0; excl[t + 256] += a1;
        __syncthreads();
    }
    int i0 = excl[t] - cnt[t], i1 = excl[t + 256] - cnt[t + 256];
    excl[t] = i0; excl[t + 256] = i1;
    cur[t] = i0; cur[t + 256] = i1;
    for (int b = t; b < NBUK; b += 256) gbase[b] = scanned[(size_t)b * NCHK + blk];
    __syncthreads();
#pragma unroll
    for (int j = 0; j < EPT; j++) {
        if (bkts[j] >= 0) {
            int pos = atomicAdd(&cur[bkts[j]], 1);
            lbuf[pos] = recs[j];
            lbkt[pos] = (unsigned short)bkts[j];
        }
    }
    __syncthreads();
    const int tot = excl[NBUK];
    for (int i = t; i < tot; i += 256) {
        int b = lbkt[i];
        staging[(size_t)gbase[b] + (i - excl[b])] = lbuf[i];
    }
}

// ---------------- CSR build: pass 3, per-bucket deg/row_off/dinv + sorted csr ------
__global__ __launch_bounds__(256) void k_phaseB2(const unsigned* __restrict__ staging,
                                                 const int* __restrict__ scanned,
                                                 float* __restrict__ dinv,
                                                 int* __restrict__ row_off,
                                                 int* __restrict__ csr) {
    __shared__ int cnt[256], excl[256], cur[256];
    __shared__ int buf[8192];
    const int t = threadIdx.x, b = blockIdx.x;
    const int node0 = b << 8;
    const int nlocal = min(256, NN - node0);
    const int seg_beg = scanned[(size_t)b * NCHK];
    const size_t nxt = (size_t)(b + 1) * NCHK;
    const int seg_end = scanned[nxt > (size_t)LCNT ? (size_t)LCNT : nxt];
    const int len = min(seg_end - seg_beg, 8192);
    cnt[t] = 0;
    __syncthreads();
    for (int i = t; i < len; i += 256) {
        unsigned r = staging[seg_beg + i];
        atomicAdd(&cnt[r >> 17], 1);
    }
    __syncthreads();
    excl[t] = cnt[t];
    __syncthreads();
    for (int off = 1; off < 256; off <<= 1) {
        int x = (t >= off) ? excl[t - off] : 0;
        __syncthreads();
        excl[t] += x;
        __syncthreads();
    }
    int ex = excl[t] - cnt[t];
    excl[t] = ex;
    cur[t] = ex;
    if (t < nlocal) {
        row_off[node0 + t] = seg_beg + ex;
        dinv[node0 + t] = rsqrtf((float)(cnt[t] + 1));  // +1 self loop
    }
    if (b == NBUK - 1 && t == 0) row_off[NN] = seg_end;
    __syncthreads();
    for (int i = t; i < len; i += 256) {
        unsigned r = staging[seg_beg + i];
        int pos = atomicAdd(&cur[r >> 17], 1);
        buf[pos] = (int)(r & 0x1FFFFu);
    }
    __syncthreads();
    for (int i = t; i < len; i += 256) csr[seg_beg + i] = buf[i];
}

// ---------------- W pack: f32 W[k][n] -> f16 frag array ----------------
template <int C>
__global__ void k_packW(const float* __restrict__ W, _Float16* __restrict__ P) {
    constexpr int NT = C / 16;
    int i = blockIdx.x * 256 + threadIdx.x;
    if (i >= 4 * NT * 512) return;
    int j = i & 7, lane = (i >> 3) & 63;
    int rest = i >> 9;
    int ct = rest % NT, kc = rest / NT;
    int k = kc * 32 + (lane >> 4) * 8 + j;
    int n = ct * 16 + (lane & 15);
    P[i] = (_Float16)W[k * C + n];
}

// ---------------- MFMA GEMM layer 1: Hf16 = f16(dinv * (x_f32 @ W)) ----------------
__global__ __launch_bounds__(256) void k_mgemm(const float* __restrict__ X,
                                               const _Float16* __restrict__ P,
                                               const float* __restrict__ dinv,
                                               unsigned short* __restrict__ H) {
    constexpr int NT = 8;
    const int tid = threadIdx.x, w = tid >> 6, lane = tid & 63;
    const int lr = lane & 15, lg = lane >> 4;
    const int row = blockIdx.x * 64 + w * 16 + lr;
    const int arow = min(row, NN - 1);
    f32x4 acc[NT];
#pragma unroll
    for (int t = 0; t < NT; t++) acc[t] = (f32x4){0.f, 0.f, 0.f, 0.f};
    const f16x8* __restrict__ Pp = (const f16x8*)P;
#pragma unroll
    for (int kc = 0; kc < 4; kc++) {
        const float* xp = X + (size_t)arow * 128 + kc * 32 + lg * 8;
        float4 x0 = *(const float4*)xp;
        float4 x1 = *(const float4*)(xp + 4);
        f16x8 a;
        a[0] = (_Float16)x0.x; a[1] = (_Float16)x0.y;
        a[2] = (_Float16)x0.z; a[3] = (_Float16)x0.w;
        a[4] = (_Float16)x1.x; a[5] = (_Float16)x1.y;
        a[6] = (_Float16)x1.z; a[7] = (_Float16)x1.w;
#pragma unroll
        for (int t = 0; t < NT; t++) {
            f16x8 b = Pp[(kc * NT + t) * 64 + lane];
            acc[t] = __builtin_amdgcn_mfma_f32_16x16x32_f16(a, b, acc[t], 0, 0, 0);
        }
    }
    const int orow0 = blockIdx.x * 64 + w * 16 + lg * 4;
    float dv[4];
#pragma unroll
    for (int r = 0; r < 4; r++) dv[r] = dinv[orow0 + r];  // pad rows: dinv=0 -> H=0
#pragma unroll
    for (int t = 0; t < NT; t++)
#pragma unroll
        for (int r = 0; r < 4; r++)
            H[(size_t)(orow0 + r) * 128 + t * 16 + lr] = f2h(acc[t][r] * dv[r]);
}

// ---------------- FUSED: agg128(+relu+bias) -> LDS -> MFMA x W_next -> G ------------
// Block = 64 dst nodes. Agg phase: 4 waves x 4 nodes x 4 iters. Gemm phase: MFMA.
template <int COUT>
__global__ __launch_bounds__(256) void k_fuse(const unsigned short* __restrict__ H,
                                              const int* __restrict__ row_off,
                                              const int* __restrict__ csr,
                                              const float* __restrict__ dinv,
                                              const float* __restrict__ bias,
                                              const _Float16* __restrict__ P,
                                              unsigned short* __restrict__ G) {
    __shared__ unsigned short T[64 * 128];  // u16x8 units: T8[row*16 + (c8 ^ (row&7))]
    const int tid = threadIdx.x, w = tid >> 6, lane = tid & 63;
    const int q = lane >> 4, il = lane & 15;
    const int nodeBase = blockIdx.x * 64;
    const u16x8* __restrict__ Hh = (const u16x8*)H;
    u16x8* __restrict__ T8 = (u16x8*)T;
    float4 b0 = *(const float4*)&bias[il * 8];
    float4 b1 = *(const float4*)&bias[il * 8 + 4];
    float ob[8] = {b0.x, b0.y, b0.z, b0.w, b1.x, b1.y, b1.z, b1.w};
    for (int it = 0; it < 4; ++it) {
        const int rloc = w * 16 + it * 4 + q;
        const int node = nodeBase + rloc;
        const int vnode = min(node, NN - 1);
        const int beg = row_off[vnode];
        int cnt = row_off[vnode + 1] - beg;
        if (node >= NN) cnt = 0;
        int m1 = max(cnt, __shfl(cnt, lane ^ 16));
        const int tmax = max(m1, __shfl(m1, lane ^ 32));
        float acc[8] = {0.f, 0.f, 0.f, 0.f, 0.f, 0.f, 0.f, 0.f};
        for (int j0 = 0; j0 < tmax; j0 += 16) {
            int sidx = vnode;
            if (j0 + il < cnt) sidx = csr[beg + j0 + il];
            const int rem = min(16, tmax - j0);
            for (int u = 0; u < rem; u += 8) {
                u16x8 v[8]; float m[8];
#pragma unroll
                for (int k = 0; k < 8; k++) {
                    int s = __shfl(sidx, q * 16 + u + k);
                    v[k] = Hh[(size_t)s * 16 + il];
                    m[k] = (j0 + u + k < cnt) ? 1.f : 0.f;
                }
#pragma unroll
                for (int k = 0; k < 8; k++)
#pragma unroll
                    for (int e = 0; e < 8; e++)
                        acc[e] = fmaf(m[k], h2f(v[k][e]), acc[e]);
            }
        }
        u16x8 hv = Hh[(size_t)vnode * 16 + il];
#pragma unroll
        for (int e = 0; e < 8; e++) acc[e] += h2f(hv[e]);
        const float dv = (node < NN) ? dinv[node] : 0.f;
        u16x8 oh;
#pragma unroll
        for (int e = 0; e < 8; e++) {
            float o = fmaf(acc[e], dv, ob[e]);
            o = fmaxf(o, 0.f);  // both fused layers have ReLU
            oh[e] = f2h(o);
        }
        T8[rloc * 16 + (il ^ (rloc & 7))] = oh;
    }
    __syncthreads();
    // ---- GEMM phase: wave w computes rows w*16..w*16+15 x W_next ----
    constexpr int NT = COUT / 16;
    const int lr = lane & 15, lg = lane >> 4;
    const int arow = w * 16 + lr;
    f32x4 acc2[NT];
#pragma unroll
    for (int t = 0; t < NT; t++) acc2[t] = (f32x4){0.f, 0.f, 0.f, 0.f};
    const f16x8* __restrict__ Pp = (const f16x8*)P;
#pragma unroll
    for (int kc = 0; kc < 4; kc++) {
        int c8 = kc * 4 + lg;
        f16x8 a = *(const f16x8*)&T8[arow * 16 + (c8 ^ (arow & 7))];
#pragma unroll
        for (int t = 0; t < NT; t++) {
            f16x8 b = Pp[(kc * NT + t) * 64 + lane];
            acc2[t] = __builtin_amdgcn_mfma_f32_16x16x32_f16(a, b, acc2[t], 0, 0, 0);
        }
    }
    const int orow0 = nodeBase + w * 16 + lg * 4;
    float dv2[4];
#pragma unroll
    for (int r = 0; r < 4; r++) dv2[r] = dinv[orow0 + r];  // pad rows -> 0
#pragma unroll
    for (int t = 0; t < NT; t++)
#pragma unroll
        for (int r = 0; r < 4; r++)
            G[(size_t)(orow0 + r) * COUT + t * 16 + lr] = f2h(acc2[t][r] * dv2[r]);
}

// ---------------- Final aggregation C=64 (f16 H): 8 nodes/wave, f32 out ------------
__global__ __launch_bounds__(256) void k_agg64(const unsigned short* __restrict__ H,
                                               const int* __restrict__ row_off,
                                               const int* __restrict__ csr,
                                               const float* __restrict__ dinv,
                                               const float* __restrict__ bias,
                                               float* __restrict__ OUT) {
    const int tid = threadIdx.x;
    const int wid = tid >> 6, lane = tid & 63;
    const int q = lane >> 3, il = lane & 7;
    const int node = blockIdx.x * 32 + wid * 8 + q;  // NN = 3125*32 exactly
    const int beg = row_off[node];
    const int cnt = row_off[node + 1] - beg;
    int m1 = max(cnt, __shfl(cnt, lane ^ 8));
    m1 = max(m1, __shfl(m1, lane ^ 16));
    const int tmax = max(m1, __shfl(m1, lane ^ 32));
    const u16x8* __restrict__ Hh = (const u16x8*)H;  // 8 u16x8 per row
    float acc[8] = {0.f, 0.f, 0.f, 0.f, 0.f, 0.f, 0.f, 0.f};
    for (int j0 = 0; j0 < tmax; j0 += 8) {
        int sidx = node;
        if (j0 + il < cnt) sidx = csr[beg + j0 + il];
        u16x8 v[8]; float m[8];
#pragma unroll
        for (int k = 0; k < 8; k++) {
            int s = __shfl(sidx, q * 8 + k);
            v[k] = Hh[(size_t)s * 8 + il];
            m[k] = (j0 + k < cnt) ? 1.f : 0.f;
        }
#pragma unroll
        for (int k = 0; k < 8; k++)
#pragma unroll
            for (int e = 0; e < 8; e++)
                acc[e] = fmaf(m[k], h2f(v[k][e]), acc[e]);
    }
    u16x8 hv = Hh[(size_t)node * 8 + il];
#pragma unroll
    for (int e = 0; e < 8; e++) acc[e] += h2f(hv[e]);
    const float dv = dinv[node];
    float4 b0 = *(const float4*)&bias[il * 8];
    float4 b1 = *(const float4*)&bias[il * 8 + 4];
    float ob[8] = {b0.x, b0.y, b0.z, b0.w, b1.x, b1.y, b1.z, b1.w};
    float4 o0, o1;
    o0.x = fmaf(acc[0], dv, ob[0]); o0.y = fmaf(acc[1], dv, ob[1]);
    o0.z = fmaf(acc[2], dv, ob[2]); o0.w = fmaf(acc[3], dv, ob[3]);
    o1.x = fmaf(acc[4], dv, ob[4]); o1.y = fmaf(acc[5], dv, ob[5]);
    o1.z = fmaf(acc[6], dv, ob[6]); o1.w = fmaf(acc[7], dv, ob[7]);
    *(float4*)&OUT[(size_t)node * 64 + il * 8] = o0;
    *(float4*)&OUT[(size_t)node * 64 + il * 8 + 4] = o1;
}

extern "C" void kernel_launch(void* const* d_in, const int* in_sizes, int n_in,
                              void* d_out, int out_size, void* d_ws, size_t ws_size,
                              hipStream_t stream) {
    const float* x  = (const float*)d_in[0];
    const void*  ei = d_in[1];
    const float* W1 = (const float*)d_in[2];
    const float* b1 = (const float*)d_in[3];
    const float* W2 = (const float*)d_in[4];
    const float* b2 = (const float*)d_in[5];
    const float* W3 = (const float*)d_in[6];
    const float* b3 = (const float*)d_in[7];
    float* out = (float*)d_out;

    char* wsp = (char*)d_ws;
    size_t off = 0;
    auto alloc = [&](size_t bytes) -> void* {
        void* p = wsp + off;
        off += (bytes + 255) & ~(size_t)255;
        return p;
    };
    unsigned short* G = (unsigned short*)alloc((size_t)NN_PAD * 128 * 2);  // H / G3 (f16)
    unsigned short* F = (unsigned short*)alloc((size_t)NN_PAD * 128 * 2);  // G2 (f16)
    float* dinv    = (float*)alloc((size_t)NN_PAD * 4);
    int*   row_off = (int*)alloc(((size_t)NN + 1) * 4);
    int*   counts  = (int*)alloc(((size_t)LCNT + 1) * 4);
    int*   bsum    = (int*)alloc(((size_t)SCB + 1) * 4);
    int*   csr     = (int*)alloc((size_t)NE * 4);
    _Float16* P1   = (_Float16*)alloc((size_t)128 * 128 * 2);
    _Float16* P2   = (_Float16*)alloc((size_t)128 * 128 * 2);
    _Float16* P3   = (_Float16*)alloc((size_t)128 * 64 * 2);
    int*   flag    = (int*)alloc(256);
    if (off > ws_size) return;

    unsigned* staging = (unsigned*)G;  // aliases G (dead until mgemm layer 1)

    k_detect_i64<<<1, 256, 0, stream>>>((const unsigned*)ei, flag, dinv);
    k_count<<<NCHK, 256, 0, stream>>>(ei, flag, counts);
    k_scan1v<<<SCB, 256, 0, stream>>>(counts, bsum);
    k_scan2v<<<1, 256, 0, stream>>>(bsum);
    k_scan3v<<<(LCNT + 1 + 255) / 256, 256, 0, stream>>>(counts, bsum);
    k_scatter2<<<NCHK, 256, 0, stream>>>(ei, flag, counts, staging);
    k_phaseB2<<<NBUK, 256, 0, stream>>>(staging, counts, dinv, row_off, csr);

    k_packW<128><<<64, 256, 0, stream>>>(W1, P1);
    k_packW<128><<<64, 256, 0, stream>>>(W2, P2);
    k_packW<64><<<32, 256, 0, stream>>>(W3, P3);

    constexpr int NBLK = NN_PAD / 64;  // 1563
    k_mgemm<<<NBLK, 256, 0, stream>>>(x, P1, dinv, G);                       // G = H1
    k_fuse<128><<<NBLK, 256, 0, stream>>>(G, row_off, csr, dinv, b1, P2, F); // F = H2
    k_fuse<64><<<NBLK, 256, 0, stream>>>(F, row_off, csr, dinv, b2, P3, G);  // G = H3 (64c)
    k_agg64<<<NN / 32, 256, 0, stream>>>(G, row_off, csr, dinv, b3, out);
}

// Round 9
// 236.130 us; speedup vs baseline: 1.0501x; 1.0394x over previous
//
#include <hip/hip_runtime.h>
#include <hip/hip_bf16.h>
#include <hip/hip_fp16.h>

#define NN 100000
#define NE 1600000
constexpr int NN_PAD = 100032;              // 64-row padded (1563 blocks)
constexpr int NBUK = (NN + 255) / 256;      // 391 dst buckets of 256 nodes
constexpr int CH   = 2048;                  // edges per chunk
constexpr int EPT  = CH / 256;              // 8 edges per thread
constexpr int NCHK = (NE + CH - 1) / CH;    // 782 chunks
constexpr int LCNT = NBUK * NCHK;           // 305,762 counters
constexpr int SCB  = (LCNT + 2047) / 2048;  // 150 scan blocks (2048/block)

typedef _Float16 f16x8 __attribute__((ext_vector_type(8)));
typedef float f32x4 __attribute__((ext_vector_type(4)));
typedef unsigned short u16x8 __attribute__((ext_vector_type(8)));

__device__ __forceinline__ float h2f(unsigned short h) {
    return __half2float(__ushort_as_half(h));
}
__device__ __forceinline__ unsigned short f2h(float f) {
    return __half_as_ushort(__float2half(f));  // RN
}

__device__ __forceinline__ int edge_at(const void* ei, int is64, long long idx) {
    if (is64) return (int)((const long long*)ei)[idx];
    return ((const int*)ei)[idx];
}

// Per-block edge-dtype self-detection: int64 data (<2^32) => odd 32-bit words zero.
// Reads first 2KB (L2-broadcast across blocks). Returns is64 (block-uniform).
// Caller must have a __syncthreads() AFTER any shared-mem init it interleaves.
__device__ __forceinline__ int detect_is64_block(const void* ei, int* s_nz) {
    const unsigned* e32 = (const unsigned*)ei;
    int nz = 0;
    for (int i = threadIdx.x; i < 512; i += 256)
        if (e32[2 * i + 1] != 0u) nz = 1;
    if (nz) *s_nz = 1;  // benign race: all writers store 1
    __syncthreads();
    return (*s_nz == 0) ? 1 : 0;
}

// ---------------- CSR build: pass 1, per-chunk LDS bucket histogram ----------------
__global__ __launch_bounds__(256) void k_count(const void* __restrict__ ei,
                                               int* __restrict__ counts) {
    __shared__ int cnt[NBUK];
    __shared__ int s_nz;
    const int t = threadIdx.x, blk = blockIdx.x;
    for (int i = t; i < NBUK; i += 256) cnt[i] = 0;
    if (t == 0) s_nz = 0;
    __syncthreads();
    const int is64 = detect_is64_block(ei, &s_nz);  // has internal sync
    const int e0 = blk * CH;
    const int elim = min(NE, e0 + CH);
#pragma unroll
    for (int j = 0; j < EPT; j++) {
        int e = e0 + j * 256 + t;
        if (e < elim) {
            int s = edge_at(ei, is64, e);
            int d = edge_at(ei, is64, (long long)NE + e);
            if ((unsigned)s < NN && (unsigned)d < NN) atomicAdd(&cnt[d >> 8], 1);
        }
    }
    __syncthreads();
    for (int i = t; i < NBUK; i += 256) counts[(size_t)i * NCHK + blk] = cnt[i];
}

// ---------------- exclusive scan of counts[LCNT] (in place), 2048/block ------------
__global__ void k_scan1v(int* __restrict__ data, int* __restrict__ bsum) {
    __shared__ int lds[256];
    int t = threadIdx.x, b = blockIdx.x;
    int base = b * 2048 + t * 8;
    int v[8], s = 0;
#pragma unroll
    for (int j = 0; j < 8; j++) {
        v[j] = (base + j < LCNT) ? data[base + j] : 0;
        s += v[j];
    }
    lds[t] = s;
    __syncthreads();
    for (int off = 1; off < 256; off <<= 1) {
        int x = (t >= off) ? lds[t - off] : 0;
        __syncthreads();
        lds[t] += x;
        __syncthreads();
    }
    int run = (t > 0) ? lds[t - 1] : 0;
    if (t == 255) bsum[b] = lds[255];
#pragma unroll
    for (int j = 0; j < 8; j++) {
        if (base + j < LCNT) data[base + j] = run;
        run += v[j];
    }
}

__global__ void k_scan2v(int* __restrict__ bsum) {
    __shared__ int lds[256];
    int t = threadIdx.x;
    int v = (t < SCB) ? bsum[t] : 0;
    lds[t] = v;
    __syncthreads();
    for (int off = 1; off < 256; off <<= 1) {
        int x = (t >= off) ? lds[t - off] : 0;
        __syncthreads();
        lds[t] += x;
        __syncthreads();
    }
    if (t < SCB) bsum[t] = lds[t] - v;     // exclusive
    if (t == SCB - 1) bsum[SCB] = lds[t];  // total valid edges
}

// ---------------- CSR build: pass 2, chunk -> LDS bucket-sort -> reserved slots ----
// Global base = counts[idx] + bsum[idx>>11]  (scan3 folded into the read).
__global__ __launch_bounds__(256) void k_scatter2(const void* __restrict__ ei,
                                                  const int* __restrict__ counts,
                                                  const int* __restrict__ bsum,
                                                  unsigned* __restrict__ staging) {
    __shared__ int cnt[512], excl[512], cur[512], gbase[512];
    __shared__ unsigned lbuf[CH];
    __shared__ unsigned short lbkt[CH];
    __shared__ int s_nz;
    const int t = threadIdx.x, blk = blockIdx.x;
    cnt[t] = 0; cnt[t + 256] = 0;
    if (t == 0) s_nz = 0;
    __syncthreads();
    const int is64 = detect_is64_block(ei, &s_nz);  // has internal sync
    const int e0 = blk * CH;
    const int elim = min(NE, e0 + CH);
    unsigned recs[EPT];
    int bkts[EPT];
#pragma unroll
    for (int j = 0; j < EPT; j++) {
        int e = e0 + j * 256 + t;
        int bk = -1; unsigned rc = 0;
        if (e < elim) {
            int s = edge_at(ei, is64, e);
            int d = edge_at(ei, is64, (long long)NE + e);
            if ((unsigned)s < NN && (unsigned)d < NN) {
                bk = d >> 8;
                rc = (unsigned)s | ((unsigned)(d & 255) << 17);
                atomicAdd(&cnt[bk], 1);
            }
        }
        recs[j] = rc; bkts[j] = bk;
    }
    __syncthreads();
    excl[t] = cnt[t]; excl[t + 256] = cnt[t + 256];
    __syncthreads();
    for (int off = 1; off < 512; off <<= 1) {
        int a0 = (t >= off) ? excl[t - off] : 0;
        int a1 = (t + 256 >= off) ? excl[t + 256 - off] : 0;
        __syncthreads();
        excl[t] += a0; excl[t + 256] += a1;
        __syncthreads();
    }
    int i0 = excl[t] - cnt[t], i1 = excl[t + 256] - cnt[t + 256];
    excl[t] = i0; excl[t + 256] = i1;
    cur[t] = i0; cur[t + 256] = i1;
    for (int bb = t; bb < NBUK; bb += 256) {
        int idx = bb * NCHK + blk;
        gbase[bb] = counts[idx] + bsum[idx >> 11];
    }
    __syncthreads();
#pragma unroll
    for (int j = 0; j < EPT; j++) {
        if (bkts[j] >= 0) {
            int pos = atomicAdd(&cur[bkts[j]], 1);
            lbuf[pos] = recs[j];
            lbkt[pos] = (unsigned short)bkts[j];
        }
    }
    __syncthreads();
    const int tot = excl[NBUK];
    for (int i = t; i < tot; i += 256) {
        int b = lbkt[i];
        staging[(size_t)gbase[b] + (i - excl[b])] = lbuf[i];
    }
}

// ---------------- CSR build: pass 3, per-bucket deg/row_off/dinv + sorted csr ------
__global__ __launch_bounds__(256) void k_phaseB2(const unsigned* __restrict__ staging,
                                                 const int* __restrict__ counts,
                                                 const int* __restrict__ bsum,
                                                 float* __restrict__ dinv,
                                                 int* __restrict__ row_off,
                                                 int* __restrict__ csr) {
    __shared__ int cnt[256], excl[256], cur[256];
    __shared__ int buf[8192];
    const int t = threadIdx.x, b = blockIdx.x;
    const int node0 = b << 8;
    const int nlocal = min(256, NN - node0);
    const int i0 = b * NCHK;
    const int seg_beg = counts[i0] + bsum[i0 >> 11];
    int seg_end;
    if (b == NBUK - 1) {
        seg_end = bsum[SCB];  // total valid edges
    } else {
        const int i1 = (b + 1) * NCHK;
        seg_end = counts[i1] + bsum[i1 >> 11];
    }
    const int len = min(seg_end - seg_beg, 8192);
    cnt[t] = 0;
    if (b == 0 && t < NN_PAD - NN) dinv[NN + t] = 0.f;  // pad rows -> 0
    __syncthreads();
    for (int i = t; i < len; i += 256) {
        unsigned r = staging[seg_beg + i];
        atomicAdd(&cnt[r >> 17], 1);
    }
    __syncthreads();
    excl[t] = cnt[t];
    __syncthreads();
    for (int off = 1; off < 256; off <<= 1) {
        int x = (t >= off) ? excl[t - off] : 0;
        __syncthreads();
        excl[t] += x;
        __syncthreads();
    }
    int ex = excl[t] - cnt[t];
    excl[t] = ex;
    cur[t] = ex;
    if (t < nlocal) {
        row_off[node0 + t] = seg_beg + ex;
        dinv[node0 + t] = rsqrtf((float)(cnt[t] + 1));  // +1 self loop
    }
    if (b == NBUK - 1 && t == 0) row_off[NN] = seg_end;
    __syncthreads();
    for (int i = t; i < len; i += 256) {
        unsigned r = staging[seg_beg + i];
        int pos = atomicAdd(&cur[r >> 17], 1);
        buf[pos] = (int)(r & 0x1FFFFu);
    }
    __syncthreads();
    for (int i = t; i < len; i += 256) csr[seg_beg + i] = buf[i];
}

// ---------------- W pack (all three weights in one kernel) ----------------
template <int C>
__device__ __forceinline__ void packone(const float* __restrict__ W,
                                        _Float16* __restrict__ P, int i) {
    constexpr int NT = C / 16;
    int j = i & 7, lane = (i >> 3) & 63;
    int rest = i >> 9;
    int ct = rest % NT, kc = rest / NT;
    int k = kc * 32 + (lane >> 4) * 8 + j;
    int n = ct * 16 + (lane & 15);
    P[i] = (_Float16)W[k * C + n];
}

__global__ void k_pack(const float* __restrict__ W1, const float* __restrict__ W2,
                       const float* __restrict__ W3, _Float16* __restrict__ P1,
                       _Float16* __restrict__ P2, _Float16* __restrict__ P3) {
    int i = blockIdx.x * 256 + threadIdx.x;
    if (i < 16384) packone<128>(W1, P1, i);
    else if (i < 32768) packone<128>(W2, P2, i - 16384);
    else if (i < 40960) packone<64>(W3, P3, i - 32768);
}

// ---------------- MFMA GEMM: Hf16[n,:] = f16(dinv[n] * (X[n,:] @ W)) ----------------
template <int C, bool F32SRC>
__global__ __launch_bounds__(256) void k_mgemm(const void* __restrict__ Xv,
                                               const _Float16* __restrict__ P,
                                               const float* __restrict__ dinv,
                                               unsigned short* __restrict__ H) {
    constexpr int NT = C / 16;
    const int tid = threadIdx.x, w = tid >> 6, lane = tid & 63;
    const int lr = lane & 15, lg = lane >> 4;
    const int row = blockIdx.x * 64 + w * 16 + lr;
    const int arow = F32SRC ? min(row, NN - 1) : row;
    f32x4 acc[NT];
#pragma unroll
    for (int t = 0; t < NT; t++) acc[t] = (f32x4){0.f, 0.f, 0.f, 0.f};
    const f16x8* __restrict__ Pp = (const f16x8*)P;
#pragma unroll
    for (int kc = 0; kc < 4; kc++) {
        f16x8 a;
        if (F32SRC) {
            const float* xp = (const float*)Xv + (size_t)arow * 128 + kc * 32 + lg * 8;
            float4 x0 = *(const float4*)xp;
            float4 x1 = *(const float4*)(xp + 4);
            a[0] = (_Float16)x0.x; a[1] = (_Float16)x0.y;
            a[2] = (_Float16)x0.z; a[3] = (_Float16)x0.w;
            a[4] = (_Float16)x1.x; a[5] = (_Float16)x1.y;
            a[6] = (_Float16)x1.z; a[7] = (_Float16)x1.w;
        } else {
            a = *(const f16x8*)((const _Float16*)Xv + (size_t)arow * 128 + kc * 32 + lg * 8);
        }
#pragma unroll
        for (int t = 0; t < NT; t++) {
            f16x8 b = Pp[(kc * NT + t) * 64 + lane];
            acc[t] = __builtin_amdgcn_mfma_f32_16x16x32_f16(a, b, acc[t], 0, 0, 0);
        }
    }
    const int orow0 = blockIdx.x * 64 + w * 16 + lg * 4;
    float dv[4];
#pragma unroll
    for (int r = 0; r < 4; r++) dv[r] = dinv[orow0 + r];  // pad rows: dinv=0 -> H=0
#pragma unroll
    for (int t = 0; t < NT; t++)
#pragma unroll
        for (int r = 0; r < 4; r++)
            H[(size_t)(orow0 + r) * C + t * 16 + lr] = f2h(acc[t][r] * dv[r]);
}

// ---------------- Aggregation C=128 (f16 H): 2 nodes/wave, 8B loads, f16 out -------
// (r6-measured best: 58 µs, VGPR 36, ~60% occupancy)
template <bool RELU>
__global__ __launch_bounds__(256) void k_agg128(const unsigned short* __restrict__ H,
                                                const int* __restrict__ row_off,
                                                const int* __restrict__ csr,
                                                const float* __restrict__ dinv,
                                                const float* __restrict__ bias,
                                                unsigned short* __restrict__ OUT) {
    const int tid = threadIdx.x;
    const int wid = tid >> 6, lane = tid & 63;
    const int half = lane >> 5, il = lane & 31;
    const int node = blockIdx.x * 8 + wid * 2 + half;  // NN = 12500*8 exactly
    const int beg = row_off[node];
    const int cnt = row_off[node + 1] - beg;
    const int tmax = max(cnt, __shfl(cnt, lane ^ 32));
    const ushort4* __restrict__ Hh = (const ushort4*)H;  // 32 ushort4 per row
    float4 acc = make_float4(0.f, 0.f, 0.f, 0.f);
    for (int j0 = 0; j0 < tmax; j0 += 32) {
        int sidx = node;
        if (j0 + il < cnt) sidx = csr[beg + j0 + il];
        const int rem = min(32, tmax - j0);
        for (int u = 0; u < rem; u += 8) {
            ushort4 v[8]; float m[8];
#pragma unroll
            for (int k = 0; k < 8; k++) {
                int s = __shfl(sidx, half * 32 + u + k);
                v[k] = Hh[(size_t)s * 32 + il];
                m[k] = (j0 + u + k < cnt) ? 1.f : 0.f;
            }
#pragma unroll
            for (int k = 0; k < 8; k++) {
                acc.x = fmaf(m[k], h2f(v[k].x), acc.x);
                acc.y = fmaf(m[k], h2f(v[k].y), acc.y);
                acc.z = fmaf(m[k], h2f(v[k].z), acc.z);
                acc.w = fmaf(m[k], h2f(v[k].w), acc.w);
            }
        }
    }
    ushort4 hv = Hh[(size_t)node * 32 + il];
    acc.x += h2f(hv.x); acc.y += h2f(hv.y);
    acc.z += h2f(hv.z); acc.w += h2f(hv.w);
    const float dv = dinv[node];
    float4 bb = ((const float4*)bias)[il];
    float ox = fmaf(acc.x, dv, bb.x), oy = fmaf(acc.y, dv, bb.y);
    float oz = fmaf(acc.z, dv, bb.z), ow = fmaf(acc.w, dv, bb.w);
    if (RELU) {
        ox = fmaxf(ox, 0.f); oy = fmaxf(oy, 0.f);
        oz = fmaxf(oz, 0.f); ow = fmaxf(ow, 0.f);
    }
    ushort4 oh;
    oh.x = f2h(ox); oh.y = f2h(oy); oh.z = f2h(oz); oh.w = f2h(ow);
    ((ushort4*)OUT)[(size_t)node * 32 + il] = oh;
}

// ---------------- Final aggregation C=64 (f16 H): 8 nodes/wave, f32 out ------------
__global__ __launch_bounds__(256) void k_agg64(const unsigned short* __restrict__ H,
                                               const int* __restrict__ row_off,
                                               const int* __restrict__ csr,
                                               const float* __restrict__ dinv,
                                               const float* __restrict__ bias,
                                               float* __restrict__ OUT) {
    const int tid = threadIdx.x;
    const int wid = tid >> 6, lane = tid & 63;
    const int q = lane >> 3, il = lane & 7;
    const int node = blockIdx.x * 32 + wid * 8 + q;  // NN = 3125*32 exactly
    const int beg = row_off[node];
    const int cnt = row_off[node + 1] - beg;
    int m1 = max(cnt, __shfl(cnt, lane ^ 8));
    m1 = max(m1, __shfl(m1, lane ^ 16));
    const int tmax = max(m1, __shfl(m1, lane ^ 32));
    const u16x8* __restrict__ Hh = (const u16x8*)H;  // 8 u16x8 per row
    float acc[8] = {0.f, 0.f, 0.f, 0.f, 0.f, 0.f, 0.f, 0.f};
    for (int j0 = 0; j0 < tmax; j0 += 8) {
        int sidx = node;
        if (j0 + il < cnt) sidx = csr[beg + j0 + il];
        u16x8 v[8]; float m[8];
#pragma unroll
        for (int k = 0; k < 8; k++) {
            int s = __shfl(sidx, q * 8 + k);
            v[k] = Hh[(size_t)s * 8 + il];
            m[k] = (j0 + k < cnt) ? 1.f : 0.f;
        }
#pragma unroll
        for (int k = 0; k < 8; k++)
#pragma unroll
            for (int e = 0; e < 8; e++)
                acc[e] = fmaf(m[k], h2f(v[k][e]), acc[e]);
    }
    u16x8 hv = Hh[(size_t)node * 8 + il];
#pragma unroll
    for (int e = 0; e < 8; e++) acc[e] += h2f(hv[e]);
    const float dv = dinv[node];
    float4 b0 = *(const float4*)&bias[il * 8];
    float4 b1 = *(const float4*)&bias[il * 8 + 4];
    float ob[8] = {b0.x, b0.y, b0.z, b0.w, b1.x, b1.y, b1.z, b1.w};
    float4 o0, o1;
    o0.x = fmaf(acc[0], dv, ob[0]); o0.y = fmaf(acc[1], dv, ob[1]);
    o0.z = fmaf(acc[2], dv, ob[2]); o0.w = fmaf(acc[3], dv, ob[3]);
    o1.x = fmaf(acc[4], dv, ob[4]); o1.y = fmaf(acc[5], dv, ob[5]);
    o1.z = fmaf(acc[6], dv, ob[6]); o1.w = fmaf(acc[7], dv, ob[7]);
    *(float4*)&OUT[(size_t)node * 64 + il * 8] = o0;
    *(float4*)&OUT[(size_t)node * 64 + il * 8 + 4] = o1;
}

extern "C" void kernel_launch(void* const* d_in, const int* in_sizes, int n_in,
                              void* d_out, int out_size, void* d_ws, size_t ws_size,
                              hipStream_t stream) {
    const float* x  = (const float*)d_in[0];
    const void*  ei = d_in[1];
    const float* W1 = (const float*)d_in[2];
    const float* b1 = (const float*)d_in[3];
    const float* W2 = (const float*)d_in[4];
    const float* b2 = (const float*)d_in[5];
    const float* W3 = (const float*)d_in[6];
    const float* b3 = (const float*)d_in[7];
    float* out = (float*)d_out;

    char* wsp = (char*)d_ws;
    size_t off = 0;
    auto alloc = [&](size_t bytes) -> void* {
        void* p = wsp + off;
        off += (bytes + 255) & ~(size_t)255;
        return p;
    };
    unsigned short* G = (unsigned short*)alloc((size_t)NN_PAD * 128 * 2);  // H1/H2' (f16)
    unsigned short* F = (unsigned short*)alloc((size_t)NN_PAD * 128 * 2);  // agg out (f16)
    float* dinv    = (float*)alloc((size_t)NN_PAD * 4);
    int*   row_off = (int*)alloc(((size_t)NN + 1) * 4);
    int*   counts  = (int*)alloc(((size_t)LCNT + 1) * 4);
    int*   bsum    = (int*)alloc(((size_t)SCB + 1) * 4);
    int*   csr     = (int*)alloc((size_t)NE * 4);
    _Float16* P1   = (_Float16*)alloc((size_t)128 * 128 * 2);
    _Float16* P2   = (_Float16*)alloc((size_t)128 * 128 * 2);
    _Float16* P3   = (_Float16*)alloc((size_t)128 * 64 * 2);
    if (off > ws_size) return;

    unsigned* staging = (unsigned*)G;  // aliases G (dead until mgemm layer 1)

    k_count<<<NCHK, 256, 0, stream>>>(ei, counts);
    k_scan1v<<<SCB, 256, 0, stream>>>(counts, bsum);
    k_scan2v<<<1, 256, 0, stream>>>(bsum);
    k_scatter2<<<NCHK, 256, 0, stream>>>(ei, counts, bsum, staging);
    k_phaseB2<<<NBUK, 256, 0, stream>>>(staging, counts, bsum, dinv, row_off, csr);
    k_pack<<<160, 256, 0, stream>>>(W1, W2, W3, P1, P2, P3);

    constexpr int NBLK = NN_PAD / 64;  // 1563
    k_mgemm<128, true><<<NBLK, 256, 0, stream>>>(x, P1, dinv, G);
    k_agg128<true><<<NN / 8, 256, 0, stream>>>(G, row_off, csr, dinv, b1, F);
    k_mgemm<128, false><<<NBLK, 256, 0, stream>>>(F, P2, dinv, G);
    k_agg128<true><<<NN / 8, 256, 0, stream>>>(G, row_off, csr, dinv, b2, F);
    k_mgemm<64, false><<<NBLK, 256, 0, stream>>>(F, P3, dinv, G);
    k_agg64<<<NN / 32, 256, 0, stream>>>(G, row_off, csr, dinv, b3, out);
}